// Round 17
// baseline (377.552 us; speedup 1.0000x reference)
//
#include <hip/hip_runtime.h>
#include <math.h>

typedef __attribute__((ext_vector_type(4))) float f32x4;
typedef __attribute__((ext_vector_type(16))) float f32x16;
typedef __attribute__((ext_vector_type(8))) short s16x8;
typedef __attribute__((ext_vector_type(8))) unsigned short u16x8;

constexpr int Bc = 4, Sc = 2048, Dc = 1024, Hc = 16, HDc = 64, Fc = 64;
constexpr int Rc = Bc * Sc;               // 8192
constexpr size_t MAT = (size_t)Rc * Dc;   // 8388608 elements
constexpr int KST = 88;                   // flash K/V LDS row stride (shorts)
constexpr int NCH = 16;                   // kv split-L chunks

__device__ __forceinline__ float bf2f(unsigned short u) {
    union { unsigned int i; float f; } v; v.i = ((unsigned int)u) << 16; return v.f;
}
__device__ __forceinline__ unsigned short f2bf(float f) {
    union { float f; unsigned int i; } v; v.f = f;
    unsigned int r = v.i + 0x7FFFu + ((v.i >> 16) & 1u);
    return (unsigned short)(r >> 16);
}
__device__ __forceinline__ unsigned cvtpk(float a, float b) {
    unsigned r;
    asm("v_cvt_pk_bf16_f32 %0, %1, %2" : "=v"(r) : "v"(a), "v"(b));
    return r;
}
// async global->LDS, 16B per lane; lds dest wave-uniform base (HW adds lane*16)
__device__ __forceinline__ void async16(const void* g, void* l) {
    __builtin_amdgcn_global_load_lds(
        (const __attribute__((address_space(1))) unsigned int*)g,
        (__attribute__((address_space(3))) unsigned int*)l, 16, 0, 0);
}

// ---------------- fused gate + x->bf16 ----------------
__global__ __launch_bounds__(256) void gate_cvt(const float* __restrict__ x,
        const float* __restrict__ gw, const float* __restrict__ gb,
        float* __restrict__ G, unsigned short* __restrict__ Y) {
    const int lane = threadIdx.x & 63;
    const int wave = threadIdx.x >> 6;
    const int r = blockIdx.x * 4 + wave;
    const size_t base = (size_t)r * Dc;
    float acc = 0.f;
    #pragma unroll
    for (int i = 0; i < 4; ++i) {
        int off = (lane + 64 * i) * 4;
        float4 v = *(const float4*)(x + base + off);
        float4 w = *(const float4*)(gw + off);
        acc += v.x * w.x + v.y * w.y + v.z * w.z + v.w * w.w;
        ushort4 o;
        o.x = f2bf(v.x); o.y = f2bf(v.y); o.z = f2bf(v.z); o.w = f2bf(v.w);
        *(ushort4*)(Y + base + off) = o;
    }
    #pragma unroll
    for (int off = 32; off > 0; off >>= 1) acc += __shfl_down(acc, off, 64);
    if (lane == 0) {
        float z = acc + gb[0];
        G[r] = 1.f / (1.f + __expf(-z));
    }
}

// ---------------- transpose+convert 1024x1024 weights (fq slot pre-scaled by QSCALE) ----------------
__global__ __launch_bounds__(256) void wtrans(
        const float* W0, const float* W1, const float* W2, const float* W3,
        const float* W4, const float* W5, const float* W6, const float* W7,
        unsigned short* T0, unsigned short* T1, unsigned short* T2, unsigned short* T3,
        unsigned short* T4, unsigned short* T5, unsigned short* T6, unsigned short* T7) {
    const float* W; unsigned short* T;
    switch (blockIdx.z) {
        case 0: W = W0; T = T0; break;  case 1: W = W1; T = T1; break;
        case 2: W = W2; T = T2; break;  case 3: W = W3; T = T3; break;
        case 4: W = W4; T = T4; break;  case 5: W = W5; T = T5; break;
        case 6: W = W6; T = T6; break;  default: W = W7; T = T7; break;
    }
    const float scale = (blockIdx.z == 0) ? (0.125f * 1.44269504f) : 1.f;  // fold flash Q-scale
    __shared__ float tile[64][65];
    const int t = threadIdx.x;
    const int r0 = blockIdx.x * 64, c0 = blockIdx.y * 64;
    #pragma unroll
    for (int i = 0; i < 4; ++i) {
        int row = (t >> 4) + 16 * i, col = (t & 15) * 4;
        float4 v = *(const float4*)(W + (size_t)(r0 + row) * 1024 + c0 + col);
        tile[row][col] = v.x * scale; tile[row][col + 1] = v.y * scale;
        tile[row][col + 2] = v.z * scale; tile[row][col + 3] = v.w * scale;
    }
    __syncthreads();
    #pragma unroll
    for (int i = 0; i < 4; ++i) {
        int orow = (t >> 4) + 16 * i, ocol = (t & 15) * 4;
        ushort4 o;
        o.x = f2bf(tile[ocol][orow]);     o.y = f2bf(tile[ocol + 1][orow]);
        o.z = f2bf(tile[ocol + 2][orow]); o.w = f2bf(tile[ocol + 3][orow]);
        *(ushort4*)(T + (size_t)(c0 + orow) * 1024 + r0 + ocol) = o;
    }
}

// ---- combined weight: W2[(h*64+f)][k] = sum_d WTin[(h*64+d)][k] * fmw[d][f] ----
__global__ __launch_bounds__(256) void w2build(const unsigned short* __restrict__ WTq,
        const unsigned short* __restrict__ WTk, const float* __restrict__ fmw,
        unsigned short* __restrict__ W2q, unsigned short* __restrict__ W2k) {
    const int h = blockIdx.x, kc = blockIdx.y, mat = blockIdx.z;
    const unsigned short* WTin = mat ? WTk : WTq;
    unsigned short* W2out = mat ? W2k : W2q;
    __shared__ float Wf[64][65];
    __shared__ float Ws[64][129];
    const int tid = threadIdx.x;
    #pragma unroll
    for (int i = 0; i < 4; ++i) {
        int idx = tid + 256 * i;
        int d = idx >> 4, c4 = (idx & 15) * 4;
        float4 v = *(const float4*)(fmw + d * 64 + c4);
        Wf[d][c4] = v.x; Wf[d][c4 + 1] = v.y; Wf[d][c4 + 2] = v.z; Wf[d][c4 + 3] = v.w;
    }
    #pragma unroll
    for (int i = 0; i < 4; ++i) {
        int idx = tid + 256 * i;
        int d = idx >> 4, c8 = (idx & 15) * 8;
        u16x8 v = *(const u16x8*)(WTin + (size_t)(h * 64 + d) * 1024 + kc * 128 + c8);
        #pragma unroll
        for (int j = 0; j < 8; ++j) Ws[d][c8 + j] = bf2f(v[j]);
    }
    __syncthreads();
    const int f = tid & 63, kw = tid >> 6;
    float acc[32];
    #pragma unroll
    for (int i = 0; i < 32; ++i) acc[i] = 0.f;
    for (int d = 0; d < 64; ++d) {
        float wf = Wf[d][f];
        #pragma unroll
        for (int i = 0; i < 32; ++i) acc[i] += wf * Ws[d][kw + 4 * i];
    }
    unsigned short* orow = W2out + (size_t)(h * 64 + f) * 1024 + kc * 128;
    #pragma unroll
    for (int i = 0; i < 32; ++i) orow[kw + 4 * i] = f2bf(acc[i]);
}

// ---- bf16 GEMM over 3 mats (WTa = mats 0,1 contiguous; WTb = mat 2), XCD-swizzled blocks.
//      If fmb != null, mats 0,1 get fused out = relu(acc + fmb[col%64]). ----
__global__ __launch_bounds__(256) void gemm3(const unsigned short* __restrict__ A,
        const unsigned short* __restrict__ WTa, const unsigned short* __restrict__ WTb,
        unsigned short* __restrict__ C0, unsigned short* __restrict__ C1,
        unsigned short* __restrict__ C2, const float* __restrict__ fmb) {
    __shared__ unsigned short As[128 * 32];
    __shared__ unsigned short Bs[128 * 32];
    const int tid = threadIdx.x, wave = tid >> 6, lane = tid & 63;
    const int lid = blockIdx.x + 64 * blockIdx.y;
    const int xcd = lid & 7, seq = lid >> 3;
    const int rp = 8 * xcd + (seq & 7);
    const int cp = seq >> 3;
    const int brow = rp * 128;
    unsigned short* C = (cp < 8) ? C0 : (cp < 16 ? C1 : C2);
    const int bcol = (cp & 7) * 128;
    const unsigned short* WT = (cp < 16) ? (WTa + (size_t)cp * 128 * 1024)
                                         : (WTb + (size_t)(cp - 16) * 128 * 1024);
    const bool doRelu = (fmb != nullptr) && (cp < 16);
    const int wm = wave >> 1, wn = wave & 1;
    const int lr = lane & 15, g8 = (lane >> 4) * 8;
    const int srow = 32 * wave + (lane >> 2);
    const int scol = (lane & 3) * 8;
    f32x4 acc[4][4];
    #pragma unroll
    for (int m = 0; m < 4; ++m)
        #pragma unroll
        for (int n = 0; n < 4; ++n) acc[m][n] = (f32x4){0.f, 0.f, 0.f, 0.f};
    for (int k0 = 0; k0 < 1024; k0 += 32) {
        __syncthreads();
        #pragma unroll
        for (int i = 0; i < 2; ++i) {
            async16(A  + (size_t)(brow + srow + 16 * i) * 1024 + k0 + scol, &As[(32 * wave + 16 * i) * 32]);
            async16(WT + (size_t)(srow + 16 * i) * 1024 + k0 + scol, &Bs[(32 * wave + 16 * i) * 32]);
        }
        __syncthreads();
        s16x8 af[4], bf[4];
        #pragma unroll
        for (int m = 0; m < 4; ++m) af[m] = *(const s16x8*)&As[(64 * wm + 16 * m + lr) * 32 + g8];
        #pragma unroll
        for (int n = 0; n < 4; ++n) bf[n] = *(const s16x8*)&Bs[(64 * wn + 16 * n + lr) * 32 + g8];
        #pragma unroll
        for (int m = 0; m < 4; ++m)
            #pragma unroll
            for (int n = 0; n < 4; ++n)
                acc[m][n] = __builtin_amdgcn_mfma_f32_16x16x32_bf16(af[m], bf[n], acc[m][n], 0, 0, 0);
    }
    const int rg = (lane >> 4) * 4;
    #pragma unroll
    for (int m = 0; m < 4; ++m)
        #pragma unroll
        for (int n = 0; n < 4; ++n) {
            float bias = doRelu ? fmb[16 * n + lr] : 0.f;
            #pragma unroll
            for (int j = 0; j < 4; ++j) {
                float v = acc[m][n][j];
                if (doRelu) v = fmaxf(v + bias, 0.f);
                C[(size_t)(brow + 64 * wm + 16 * m + rg + j) * 1024 + bcol + 64 * wn + 16 * n + lr] =
                    f2bf(v);
            }
        }
}

// ---------------- final dual GEMM (XCD-swizzled) ----------------
__global__ __launch_bounds__(256) void final_gemm(const unsigned short* __restrict__ A1,
        const unsigned short* __restrict__ WT1, const unsigned short* __restrict__ A2,
        const unsigned short* __restrict__ WT2, const float* __restrict__ b1,
        const float* __restrict__ b2, const float* __restrict__ G, float* __restrict__ OUT) {
    __shared__ unsigned short As[128 * 32];
    __shared__ unsigned short Bs[128 * 32];
    const int tid = threadIdx.x, wave = tid >> 6, lane = tid & 63;
    const int lid = blockIdx.x + 64 * blockIdx.y;
    const int xcd = lid & 7, seq = lid >> 3;
    const int brow = (8 * xcd + (seq & 7)) * 128;
    const int bcol = (seq >> 3) * 128;
    const int wm = wave >> 1, wn = wave & 1;
    const int lr = lane & 15, g8 = (lane >> 4) * 8;
    const int srow = 32 * wave + (lane >> 2);
    const int scol = (lane & 3) * 8;
    f32x4 acc[4][4];
    #pragma unroll
    for (int m = 0; m < 4; ++m)
        #pragma unroll
        for (int n = 0; n < 4; ++n) acc[m][n] = (f32x4){0.f, 0.f, 0.f, 0.f};
    for (int pass = 0; pass < 2; ++pass) {
        const unsigned short* A  = pass ? A2 : A1;
        const unsigned short* WT = pass ? WT2 : WT1;
        for (int k0 = 0; k0 < 1024; k0 += 32) {
            __syncthreads();
            #pragma unroll
            for (int i = 0; i < 2; ++i) {
                async16(A  + (size_t)(brow + srow + 16 * i) * 1024 + k0 + scol, &As[(32 * wave + 16 * i) * 32]);
                async16(WT + (size_t)(bcol + srow + 16 * i) * 1024 + k0 + scol, &Bs[(32 * wave + 16 * i) * 32]);
            }
            __syncthreads();
            s16x8 af[4], bf[4];
            #pragma unroll
            for (int m = 0; m < 4; ++m) af[m] = *(const s16x8*)&As[(64 * wm + 16 * m + lr) * 32 + g8];
            #pragma unroll
            for (int n = 0; n < 4; ++n) bf[n] = *(const s16x8*)&Bs[(64 * wn + 16 * n + lr) * 32 + g8];
            #pragma unroll
            for (int m = 0; m < 4; ++m)
                #pragma unroll
                for (int n = 0; n < 4; ++n)
                    acc[m][n] = __builtin_amdgcn_mfma_f32_16x16x32_bf16(af[m], bf[n], acc[m][n], 0, 0, 0);
        }
    }
    const int rg = (lane >> 4) * 4;
    #pragma unroll
    for (int m = 0; m < 4; ++m)
        #pragma unroll
        for (int j = 0; j < 4; ++j) {
            int row = brow + 64 * wm + 16 * m + rg + j;
            float g = G[row];
            #pragma unroll
            for (int n = 0; n < 4; ++n) {
                int col = bcol + 64 * wn + 16 * n + lr;
                OUT[(size_t)row * 1024 + col] = acc[m][n][j] + g * b1[col] + (1.f - g) * b2[col];
            }
        }
}

// ---------------- MFMA flash attention (reg-staged K/V, stride 88; Q pre-scaled in weights) ----------------
__global__ __launch_bounds__(512) void flash_mfma(const unsigned short* __restrict__ Qg,
        const unsigned short* __restrict__ Kg, const unsigned short* __restrict__ Vg,
        const float* __restrict__ G, unsigned short* __restrict__ FA) {
    __shared__ unsigned short Ks[2][64 * KST];   // K rows (stride 88: bank-floor)
    __shared__ unsigned short Vt[2][64 * KST];   // Vt[d][perm(k)-granule ^ (d>>3)]
    const int tid = threadIdx.x, wave = tid >> 6, lane = tid & 63;
    const int b = blockIdx.x >> 4, h = blockIdx.x & 15, q0 = blockIdx.y * 256;
    const int lq = lane & 31, hi = lane >> 5;
    const size_t qrow = (size_t)b * Sc + q0 + wave * 32 + lq;
    const size_t qoff = qrow * Dc + h * HDc + 8 * hi;
    s16x8 aq[4];
    #pragma unroll
    for (int dc = 0; dc < 4; ++dc)
        aq[dc] = *(const s16x8*)(Qg + qoff + 16 * dc);   // already scaled by 0.125*log2e via wtrans
    const s16x8 ones = {0x3F80, 0x3F80, 0x3F80, 0x3F80, 0x3F80, 0x3F80, 0x3F80, 0x3F80};
    f32x16 oacc[2], lacc;
    #pragma unroll
    for (int t = 0; t < 2; ++t)
        #pragma unroll
        for (int r = 0; r < 16; ++r) oacc[t][r] = 0.f;
    #pragma unroll
    for (int r = 0; r < 16; ++r) lacc[r] = 0.f;
    const int srow = tid >> 3, sc8 = (tid & 7) * 8, va = tid & 7;
    const int p0 = (srow & 3) | (((srow >> 3) & 1) << 2) | (((srow >> 2) & 1) << 3) | (srow & 0x30);
    const int pg = p0 >> 3, pin = p0 & 7;
    const size_t kvoff = (size_t)h * HDc + sc8;
    {
        size_t gg = ((size_t)b * Sc + srow) * Dc + kvoff;
        u16x8 kreg = *(const u16x8*)(Kg + gg);
        u16x8 vreg = *(const u16x8*)(Vg + gg);
        *(u16x8*)&Ks[0][srow * KST + sc8] = kreg;
        #pragma unroll
        for (int j = 0; j < 8; ++j)
            Vt[0][(sc8 + j) * KST + 8 * (pg ^ va) + pin] = vreg[j];
    }
    __syncthreads();
    int cur = 0;
    for (int t0 = 0; t0 < Sc; t0 += 64) {
        const bool nxt = (t0 + 64) < Sc;
        u16x8 kn, vn;
        if (nxt) {
            size_t gg = ((size_t)b * Sc + t0 + 64 + srow) * Dc + kvoff;
            kn = *(const u16x8*)(Kg + gg);
            vn = *(const u16x8*)(Vg + gg);
        }
        f32x16 s2[2];
        #pragma unroll
        for (int t = 0; t < 2; ++t)
            #pragma unroll
            for (int r = 0; r < 16; ++r) s2[t][r] = 0.f;
        __builtin_amdgcn_s_setprio(1);
        #pragma unroll
        for (int kt2 = 0; kt2 < 2; ++kt2)
            #pragma unroll
            for (int dc = 0; dc < 4; ++dc) {
                s16x8 ak = *(const s16x8*)&Ks[cur][(32 * kt2 + lq) * KST + 16 * dc + 8 * hi];
                s2[kt2] = __builtin_amdgcn_mfma_f32_32x32x16_bf16(ak, aq[dc], s2[kt2], 0, 0, 0);
            }
        __builtin_amdgcn_s_setprio(0);
        #pragma unroll
        for (int t = 0; t < 2; ++t)
            #pragma unroll
            for (int r = 0; r < 16; ++r)
                s2[t][r] = exp2f(s2[t][r]);
        s16x8 pf[4];
        #pragma unroll
        for (int kc = 0; kc < 4; ++kc) {
            const int t = kc >> 1, e = 8 * (kc & 1);
            union { s16x8 v; unsigned u[4]; } w;
            w.u[0] = cvtpk(s2[t][e + 0], s2[t][e + 1]);
            w.u[1] = cvtpk(s2[t][e + 2], s2[t][e + 3]);
            w.u[2] = cvtpk(s2[t][e + 4], s2[t][e + 5]);
            w.u[3] = cvtpk(s2[t][e + 6], s2[t][e + 7]);
            pf[kc] = w.v;
        }
        __builtin_amdgcn_s_setprio(1);
        #pragma unroll
        for (int dtile = 0; dtile < 2; ++dtile) {
            const int row = 32 * dtile + lq;
            const int rsw = (row >> 3) & 7;
            #pragma unroll
            for (int kc = 0; kc < 4; ++kc) {
                const int g = 4 * (kc >> 1) + 2 * (kc & 1) + hi;
                s16x8 av = *(const s16x8*)&Vt[cur][row * KST + 8 * (g ^ rsw)];
                oacc[dtile] = __builtin_amdgcn_mfma_f32_32x32x16_bf16(av, pf[kc], oacc[dtile], 0, 0, 0);
            }
        }
        #pragma unroll
        for (int kc = 0; kc < 4; ++kc)
            lacc = __builtin_amdgcn_mfma_f32_32x32x16_bf16(ones, pf[kc], lacc, 0, 0, 0);
        __builtin_amdgcn_s_setprio(0);
        if (nxt) {
            *(u16x8*)&Ks[cur ^ 1][srow * KST + sc8] = kn;
            #pragma unroll
            for (int j = 0; j < 8; ++j)
                Vt[cur ^ 1][(sc8 + j) * KST + 8 * (pg ^ va) + pin] = vn[j];
        }
        __syncthreads();
        cur ^= 1;
    }
    const float scl = G[qrow] / lacc[0];
    #pragma unroll
    for (int dtile = 0; dtile < 2; ++dtile)
        #pragma unroll
        for (int s = 0; s < 4; ++s) {
            ushort4 o4;
            o4.x = f2bf(oacc[dtile][4 * s + 0] * scl);
            o4.y = f2bf(oacc[dtile][4 * s + 1] * scl);
            o4.z = f2bf(oacc[dtile][4 * s + 2] * scl);
            o4.w = f2bf(oacc[dtile][4 * s + 3] * scl);
            *(ushort4*)(FA + qrow * Dc + h * HDc + 32 * dtile + 8 * s + 4 * hi) = o4;
        }
}

// ---------------- kv stage 1: per-(bh, l-chunk) partial sums ----------------
__global__ __launch_bounds__(256) void kv_part(const unsigned short* __restrict__ KF,
        const unsigned short* __restrict__ VL, float* __restrict__ PART, float* __restrict__ PARTS) {
    __shared__ float Ks[32][68];
    __shared__ float Vs[32][68];
    const int tid = threadIdx.x;
    const int bh = blockIdx.x;
    const int b = bh >> 4, h = bh & 15;
    const int ch = blockIdx.y;
    const int f = tid >> 2;
    const int dg = (tid & 3) << 4;
    float acc[16] = {};
    float ksum = 0.f;
    const int lbeg = ch * (Sc / NCH), lend = lbeg + Sc / NCH;
    for (int l0 = lbeg; l0 < lend; l0 += 32) {
        __syncthreads();
        for (int i = tid; i < 32 * 64 / 4; i += 256) {
            int r = i >> 4, c = (i & 15) << 2;
            size_t gg = ((size_t)(b * Sc + l0 + r) * Hc + h) * 64 + c;
            ushort4 kk = *(const ushort4*)(KF + gg);
            ushort4 vv = *(const ushort4*)(VL + gg);
            Ks[r][c] = bf2f(kk.x); Ks[r][c + 1] = bf2f(kk.y);
            Ks[r][c + 2] = bf2f(kk.z); Ks[r][c + 3] = bf2f(kk.w);
            Vs[r][c] = bf2f(vv.x); Vs[r][c + 1] = bf2f(vv.y);
            Vs[r][c + 2] = bf2f(vv.z); Vs[r][c + 3] = bf2f(vv.w);
        }
        __syncthreads();
        #pragma unroll 4
        for (int ll = 0; ll < 32; ++ll) {
            float kf = Ks[ll][f];
            ksum += kf;
            float4 v0 = *(const float4*)&Vs[ll][dg];
            float4 v1 = *(const float4*)&Vs[ll][dg + 4];
            float4 v2 = *(const float4*)&Vs[ll][dg + 8];
            float4 v3 = *(const float4*)&Vs[ll][dg + 12];
            acc[0] += kf * v0.x; acc[1] += kf * v0.y; acc[2]  += kf * v0.z; acc[3]  += kf * v0.w;
            acc[4] += kf * v1.x; acc[5] += kf * v1.y; acc[6]  += kf * v1.z; acc[7]  += kf * v1.w;
            acc[8] += kf * v2.x; acc[9] += kf * v2.y; acc[10] += kf * v2.z; acc[11] += kf * v2.w;
            acc[12] += kf * v3.x; acc[13] += kf * v3.y; acc[14] += kf * v3.z; acc[15] += kf * v3.w;
        }
    }
    size_t o = (((size_t)ch * 64 + bh) * 64 + f) * 64 + dg;
    *(float4*)(PART + o)      = make_float4(acc[0], acc[1], acc[2], acc[3]);
    *(float4*)(PART + o + 4)  = make_float4(acc[4], acc[5], acc[6], acc[7]);
    *(float4*)(PART + o + 8)  = make_float4(acc[8], acc[9], acc[10], acc[11]);
    *(float4*)(PART + o + 12) = make_float4(acc[12], acc[13], acc[14], acc[15]);
    if ((tid & 3) == 0) PARTS[((size_t)ch * 64 + bh) * 64 + f] = ksum;
}

// ---------------- KVB build: coalesced chunk-reduce into LDS, then LDS-transposed write ----------------
__global__ __launch_bounds__(256) void kvb_build(const float* __restrict__ PART,
        const float* __restrict__ PARTS, unsigned short* __restrict__ KVB) {
    __shared__ float accs[4096];    // [f][n] layout = f*64 + n
    const int bh = blockIdx.x, t = threadIdx.x;
    for (int i = t; i < 4096; i += 256) {
        float v = 0.f;
        #pragma unroll
        for (int ch = 0; ch < NCH; ++ch)
            v += PART[(size_t)ch * 262144 + (size_t)bh * 4096 + i];
        accs[i] = v;
    }
    __syncthreads();
    for (int i = t; i < 80 * 64; i += 256) {
        int n = i >> 6, f = i & 63;
        float v;
        if (n < 64) {
            v = accs[f * 64 + n];
        } else if (n == 64) {
            v = 0.f;
            #pragma unroll
            for (int ch = 0; ch < NCH; ++ch)
                v += PARTS[(size_t)ch * 4096 + bh * 64 + f];
        } else {
            v = 0.f;
        }
        KVB[(size_t)bh * 5120 + i] = f2bf(v);
    }
}

// ---------------- lin via MFMA ----------------
__global__ __launch_bounds__(256) void lin_mfma(const unsigned short* __restrict__ QF,
        const unsigned short* __restrict__ KVB, const float* __restrict__ G,
        unsigned short* __restrict__ LA) {
    __shared__ unsigned short As[128 * 72];
    __shared__ unsigned short Bs[80 * 72];
    const int tid = threadIdx.x, wave = tid >> 6, lane = tid & 63;
    const int bh = blockIdx.y, b = bh >> 4, h = bh & 15;
    const size_t rowg0 = (size_t)b * Sc + blockIdx.x * 128;
    #pragma unroll
    for (int i = 0; i < 4; ++i) {
        int idx = tid + 256 * i;
        int r = idx >> 3, c8 = (idx & 7) * 8;
        *(u16x8*)&As[r * 72 + c8] = *(const u16x8*)(QF + (rowg0 + r) * 1024 + h * 64 + c8);
    }
    #pragma unroll
    for (int i = 0; i < 3; ++i) {
        int idx = tid + 256 * i;
        if (idx < 640) {
            int r = idx >> 3, c8 = (idx & 7) * 8;
            *(u16x8*)&Bs[r * 72 + c8] = *(const u16x8*)(KVB + (size_t)bh * 5120 + r * 64 + c8);
        }
    }
    __syncthreads();
    const int lr = lane & 15, g8 = (lane >> 4) * 8;
    f32x4 acc[2][5];
    #pragma unroll
    for (int m = 0; m < 2; ++m)
        #pragma unroll
        for (int n = 0; n < 5; ++n) acc[m][n] = (f32x4){0.f, 0.f, 0.f, 0.f};
    #pragma unroll
    for (int kc = 0; kc < 2; ++kc) {
        s16x8 af[2];
        #pragma unroll
        for (int m = 0; m < 2; ++m)
            af[m] = *(const s16x8*)&As[(32 * wave + 16 * m + lr) * 72 + kc * 32 + g8];
        #pragma unroll
        for (int n = 0; n < 5; ++n) {
            s16x8 bfv = *(const s16x8*)&Bs[(16 * n + lr) * 72 + kc * 32 + g8];
            #pragma unroll
            for (int m = 0; m < 2; ++m)
                acc[m][n] = __builtin_amdgcn_mfma_f32_16x16x32_bf16(af[m], bfv, acc[m][n], 0, 0, 0);
        }
    }
    const int rg = (lane >> 4) * 4;
    #pragma unroll
    for (int m = 0; m < 2; ++m)
        #pragma unroll
        for (int j = 0; j < 4; ++j) {
            size_t rglob = rowg0 + 32 * wave + 16 * m + rg + j;
            float g = G[rglob];
            float nv = __shfl(acc[m][4][j], lane & 48, 64);
            float inv = (1.f - g) / fmaxf(nv, 1e-6f);
            #pragma unroll
            for (int n = 0; n < 4; ++n)
                LA[rglob * 1024 + h * 64 + 16 * n + lr] = f2bf(acc[m][n][j] * inv);
        }
}

extern "C" void kernel_launch(void* const* d_in, const int* in_sizes, int n_in,
                              void* d_out, int out_size, void* d_ws, size_t ws_size,
                              hipStream_t stream) {
    const float* x   = (const float*)d_in[0];
    const float* fq  = (const float*)d_in[1];
    const float* fk  = (const float*)d_in[2];
    const float* fv  = (const float*)d_in[3];
    const float* fow = (const float*)d_in[4];
    const float* fob = (const float*)d_in[5];
    const float* lq  = (const float*)d_in[6];
    const float* lk  = (const float*)d_in[7];
    const float* lv  = (const float*)d_in[8];
    const float* low = (const float*)d_in[9];
    const float* lob = (const float*)d_in[10];
    const float* fmw = (const float*)d_in[11];
    const float* fmb = (const float*)d_in[12];
    const float* gw  = (const float*)d_in[13];
    const float* gb  = (const float*)d_in[14];
    float* out = (float*)d_out;

    char* p = (char*)d_ws;
    unsigned short* xb = (unsigned short*)p;          p += MAT * 2;
    unsigned short* wt_fq = (unsigned short*)p;       p += (size_t)1024 * 1024 * 2;
    unsigned short* wt_fk = (unsigned short*)p;       p += (size_t)1024 * 1024 * 2;
    unsigned short* wt_fv = (unsigned short*)p;       p += (size_t)1024 * 1024 * 2;
    unsigned short* wt_fo = (unsigned short*)p;       p += (size_t)1024 * 1024 * 2;
    unsigned short* wt_lq = (unsigned short*)p;       p += (size_t)1024 * 1024 * 2;
    unsigned short* wt_lk = (unsigned short*)p;       p += (size_t)1024 * 1024 * 2;
    unsigned short* wt_lv = (unsigned short*)p;       p += (size_t)1024 * 1024 * 2;
    unsigned short* wt_lo = (unsigned short*)p;       p += (size_t)1024 * 1024 * 2;
    unsigned short* P0 = (unsigned short*)p;          p += MAT * 2;
    unsigned short* P1 = (unsigned short*)p;          p += MAT * 2;
    unsigned short* P2 = (unsigned short*)p;          p += MAT * 2;
    unsigned short* FA = (unsigned short*)p;          p += MAT * 2;
    unsigned short* LA = (unsigned short*)p;          p += MAT * 2;
    float* G  = (float*)p;                            p += (size_t)Rc * 4;
    float* PART  = (float*)p;                         p += (size_t)NCH * 64 * 64 * 64 * 4;
    float* PARTS = (float*)p;                         p += (size_t)NCH * 64 * 64 * 4;
    unsigned short* KVB = (unsigned short*)p;         p += (size_t)64 * 80 * 64 * 2;
    unsigned short* W2  = (unsigned short*)p;         p += (size_t)2 * 1024 * 1024 * 2;

    gate_cvt<<<Rc / 4, 256, 0, stream>>>(x, gw, gb, G, xb);
    wtrans<<<dim3(16, 16, 8), 256, 0, stream>>>(fq, fk, fv, fow, lq, lk, lv, low,
            wt_fq, wt_fk, wt_fv, wt_fo, wt_lq, wt_lk, wt_lv, wt_lo);
    w2build<<<dim3(16, 8, 2), 256, 0, stream>>>(wt_lq, wt_lk, fmw, W2, W2 + (size_t)1024 * 1024);

    // linear path: qf/kf computed directly with fused relu+bias (featmap folded into W2)
    gemm3<<<dim3(64, 24), 256, 0, stream>>>(xb, W2, wt_lv, P0, P1, P2, fmb);
    kv_part<<<dim3(Bc * Hc, NCH), 256, 0, stream>>>(P1, P2, PART, PARTS);
    kvb_build<<<64, 256, 0, stream>>>(PART, PARTS, KVB);
    lin_mfma<<<dim3(Sc / 128, 64), 256, 0, stream>>>(P0, KVB, G, LA);

    // flash path (reuses P0..P2; wt_fq pre-scaled so flash Q needs no rescale)
    gemm3<<<dim3(64, 24), 256, 0, stream>>>(xb, wt_fq, wt_fv, P0, P1, P2, nullptr);
    flash_mfma<<<dim3(64, 8), 512, 0, stream>>>(P0, P1, P2, G, FA);

    // fused gated output projection
    final_gemm<<<dim3(64, 8), 256, 0, stream>>>(FA, wt_fo, LA, wt_lo, fob, lob, G, out);
}

// Round 18
// 368.618 us; speedup vs baseline: 1.0242x; 1.0242x over previous
//
#include <hip/hip_runtime.h>
#include <math.h>

typedef __attribute__((ext_vector_type(4))) float f32x4;
typedef __attribute__((ext_vector_type(16))) float f32x16;
typedef __attribute__((ext_vector_type(8))) short s16x8;
typedef __attribute__((ext_vector_type(8))) unsigned short u16x8;

constexpr int Bc = 4, Sc = 2048, Dc = 1024, Hc = 16, HDc = 64, Fc = 64;
constexpr int Rc = Bc * Sc;               // 8192
constexpr size_t MAT = (size_t)Rc * Dc;   // 8388608 elements
constexpr int KST = 88;                   // flash K/V LDS row stride (shorts)
constexpr int NCH = 16;                   // kv split-L chunks

__device__ __forceinline__ float bf2f(unsigned short u) {
    union { unsigned int i; float f; } v; v.i = ((unsigned int)u) << 16; return v.f;
}
__device__ __forceinline__ unsigned short f2bf(float f) {
    union { float f; unsigned int i; } v; v.f = f;
    unsigned int r = v.i + 0x7FFFu + ((v.i >> 16) & 1u);
    return (unsigned short)(r >> 16);
}
__device__ __forceinline__ unsigned cvtpk(float a, float b) {
    unsigned r;
    asm("v_cvt_pk_bf16_f32 %0, %1, %2" : "=v"(r) : "v"(a), "v"(b));
    return r;
}
// async global->LDS, 16B per lane; lds dest wave-uniform base (HW adds lane*16)
__device__ __forceinline__ void async16(const void* g, void* l) {
    __builtin_amdgcn_global_load_lds(
        (const __attribute__((address_space(1))) unsigned int*)g,
        (__attribute__((address_space(3))) unsigned int*)l, 16, 0, 0);
}

// ---------------- fused gate + x->bf16 ----------------
__global__ __launch_bounds__(256) void gate_cvt(const float* __restrict__ x,
        const float* __restrict__ gw, const float* __restrict__ gb,
        float* __restrict__ G, unsigned short* __restrict__ Y) {
    const int lane = threadIdx.x & 63;
    const int wave = threadIdx.x >> 6;
    const int r = blockIdx.x * 4 + wave;
    const size_t base = (size_t)r * Dc;
    float acc = 0.f;
    #pragma unroll
    for (int i = 0; i < 4; ++i) {
        int off = (lane + 64 * i) * 4;
        float4 v = *(const float4*)(x + base + off);
        float4 w = *(const float4*)(gw + off);
        acc += v.x * w.x + v.y * w.y + v.z * w.z + v.w * w.w;
        ushort4 o;
        o.x = f2bf(v.x); o.y = f2bf(v.y); o.z = f2bf(v.z); o.w = f2bf(v.w);
        *(ushort4*)(Y + base + off) = o;
    }
    #pragma unroll
    for (int off = 32; off > 0; off >>= 1) acc += __shfl_down(acc, off, 64);
    if (lane == 0) {
        float z = acc + gb[0];
        G[r] = 1.f / (1.f + __expf(-z));
    }
}

// ---------------- transpose+convert 1024x1024 weights ----------------
__global__ __launch_bounds__(256) void wtrans(
        const float* W0, const float* W1, const float* W2, const float* W3,
        const float* W4, const float* W5, const float* W6, const float* W7,
        unsigned short* T0, unsigned short* T1, unsigned short* T2, unsigned short* T3,
        unsigned short* T4, unsigned short* T5, unsigned short* T6, unsigned short* T7) {
    const float* W; unsigned short* T;
    switch (blockIdx.z) {
        case 0: W = W0; T = T0; break;  case 1: W = W1; T = T1; break;
        case 2: W = W2; T = T2; break;  case 3: W = W3; T = T3; break;
        case 4: W = W4; T = T4; break;  case 5: W = W5; T = T5; break;
        case 6: W = W6; T = T6; break;  default: W = W7; T = T7; break;
    }
    __shared__ float tile[64][65];
    const int t = threadIdx.x;
    const int r0 = blockIdx.x * 64, c0 = blockIdx.y * 64;
    #pragma unroll
    for (int i = 0; i < 4; ++i) {
        int row = (t >> 4) + 16 * i, col = (t & 15) * 4;
        float4 v = *(const float4*)(W + (size_t)(r0 + row) * 1024 + c0 + col);
        tile[row][col] = v.x; tile[row][col + 1] = v.y;
        tile[row][col + 2] = v.z; tile[row][col + 3] = v.w;
    }
    __syncthreads();
    #pragma unroll
    for (int i = 0; i < 4; ++i) {
        int orow = (t >> 4) + 16 * i, ocol = (t & 15) * 4;
        ushort4 o;
        o.x = f2bf(tile[ocol][orow]);     o.y = f2bf(tile[ocol + 1][orow]);
        o.z = f2bf(tile[ocol + 2][orow]); o.w = f2bf(tile[ocol + 3][orow]);
        *(ushort4*)(T + (size_t)(c0 + orow) * 1024 + r0 + ocol) = o;
    }
}

// ---- combined weight: W2[(h*64+f)][k] = sum_d WTin[(h*64+d)][k] * fmw[d][f] ----
__global__ __launch_bounds__(256) void w2build(const unsigned short* __restrict__ WTq,
        const unsigned short* __restrict__ WTk, const float* __restrict__ fmw,
        unsigned short* __restrict__ W2q, unsigned short* __restrict__ W2k) {
    const int h = blockIdx.x, kc = blockIdx.y, mat = blockIdx.z;
    const unsigned short* WTin = mat ? WTk : WTq;
    unsigned short* W2out = mat ? W2k : W2q;
    __shared__ float Wf[64][65];
    __shared__ float Ws[64][129];
    const int tid = threadIdx.x;
    #pragma unroll
    for (int i = 0; i < 4; ++i) {
        int idx = tid + 256 * i;
        int d = idx >> 4, c4 = (idx & 15) * 4;
        float4 v = *(const float4*)(fmw + d * 64 + c4);
        Wf[d][c4] = v.x; Wf[d][c4 + 1] = v.y; Wf[d][c4 + 2] = v.z; Wf[d][c4 + 3] = v.w;
    }
    #pragma unroll
    for (int i = 0; i < 4; ++i) {
        int idx = tid + 256 * i;
        int d = idx >> 4, c8 = (idx & 15) * 8;
        u16x8 v = *(const u16x8*)(WTin + (size_t)(h * 64 + d) * 1024 + kc * 128 + c8);
        #pragma unroll
        for (int j = 0; j < 8; ++j) Ws[d][c8 + j] = bf2f(v[j]);
    }
    __syncthreads();
    const int f = tid & 63, kw = tid >> 6;
    float acc[32];
    #pragma unroll
    for (int i = 0; i < 32; ++i) acc[i] = 0.f;
    for (int d = 0; d < 64; ++d) {
        float wf = Wf[d][f];
        #pragma unroll
        for (int i = 0; i < 32; ++i) acc[i] += wf * Ws[d][kw + 4 * i];
    }
    unsigned short* orow = W2out + (size_t)(h * 64 + f) * 1024 + kc * 128;
    #pragma unroll
    for (int i = 0; i < 32; ++i) orow[kw + 4 * i] = f2bf(acc[i]);
}

// ---- bf16 GEMM over 3 mats (WTa = mats 0,1 contiguous; WTb = mat 2), XCD-swizzled blocks.
//      If fmb != null, mats 0,1 get fused out = relu(acc + fmb[col%64]). ----
__global__ __launch_bounds__(256) void gemm3(const unsigned short* __restrict__ A,
        const unsigned short* __restrict__ WTa, const unsigned short* __restrict__ WTb,
        unsigned short* __restrict__ C0, unsigned short* __restrict__ C1,
        unsigned short* __restrict__ C2, const float* __restrict__ fmb) {
    __shared__ unsigned short As[128 * 32];
    __shared__ unsigned short Bs[128 * 32];
    const int tid = threadIdx.x, wave = tid >> 6, lane = tid & 63;
    const int lid = blockIdx.x + 64 * blockIdx.y;
    const int xcd = lid & 7, seq = lid >> 3;
    const int rp = 8 * xcd + (seq & 7);
    const int cp = seq >> 3;
    const int brow = rp * 128;
    unsigned short* C = (cp < 8) ? C0 : (cp < 16 ? C1 : C2);
    const int bcol = (cp & 7) * 128;
    const unsigned short* WT = (cp < 16) ? (WTa + (size_t)cp * 128 * 1024)
                                         : (WTb + (size_t)(cp - 16) * 128 * 1024);
    const bool doRelu = (fmb != nullptr) && (cp < 16);
    const int wm = wave >> 1, wn = wave & 1;
    const int lr = lane & 15, g8 = (lane >> 4) * 8;
    const int srow = 32 * wave + (lane >> 2);
    const int scol = (lane & 3) * 8;
    f32x4 acc[4][4];
    #pragma unroll
    for (int m = 0; m < 4; ++m)
        #pragma unroll
        for (int n = 0; n < 4; ++n) acc[m][n] = (f32x4){0.f, 0.f, 0.f, 0.f};
    for (int k0 = 0; k0 < 1024; k0 += 32) {
        __syncthreads();
        #pragma unroll
        for (int i = 0; i < 2; ++i) {
            async16(A  + (size_t)(brow + srow + 16 * i) * 1024 + k0 + scol, &As[(32 * wave + 16 * i) * 32]);
            async16(WT + (size_t)(srow + 16 * i) * 1024 + k0 + scol, &Bs[(32 * wave + 16 * i) * 32]);
        }
        __syncthreads();
        s16x8 af[4], bf[4];
        #pragma unroll
        for (int m = 0; m < 4; ++m) af[m] = *(const s16x8*)&As[(64 * wm + 16 * m + lr) * 32 + g8];
        #pragma unroll
        for (int n = 0; n < 4; ++n) bf[n] = *(const s16x8*)&Bs[(64 * wn + 16 * n + lr) * 32 + g8];
        #pragma unroll
        for (int m = 0; m < 4; ++m)
            #pragma unroll
            for (int n = 0; n < 4; ++n)
                acc[m][n] = __builtin_amdgcn_mfma_f32_16x16x32_bf16(af[m], bf[n], acc[m][n], 0, 0, 0);
    }
    const int rg = (lane >> 4) * 4;
    #pragma unroll
    for (int m = 0; m < 4; ++m)
        #pragma unroll
        for (int n = 0; n < 4; ++n) {
            float bias = doRelu ? fmb[16 * n + lr] : 0.f;
            #pragma unroll
            for (int j = 0; j < 4; ++j) {
                float v = acc[m][n][j];
                if (doRelu) v = fmaxf(v + bias, 0.f);
                C[(size_t)(brow + 64 * wm + 16 * m + rg + j) * 1024 + bcol + 64 * wn + 16 * n + lr] =
                    f2bf(v);
            }
        }
}

// ---------------- final dual GEMM (XCD-swizzled) ----------------
__global__ __launch_bounds__(256) void final_gemm(const unsigned short* __restrict__ A1,
        const unsigned short* __restrict__ WT1, const unsigned short* __restrict__ A2,
        const unsigned short* __restrict__ WT2, const float* __restrict__ b1,
        const float* __restrict__ b2, const float* __restrict__ G, float* __restrict__ OUT) {
    __shared__ unsigned short As[128 * 32];
    __shared__ unsigned short Bs[128 * 32];
    const int tid = threadIdx.x, wave = tid >> 6, lane = tid & 63;
    const int lid = blockIdx.x + 64 * blockIdx.y;
    const int xcd = lid & 7, seq = lid >> 3;
    const int brow = (8 * xcd + (seq & 7)) * 128;
    const int bcol = (seq >> 3) * 128;
    const int wm = wave >> 1, wn = wave & 1;
    const int lr = lane & 15, g8 = (lane >> 4) * 8;
    const int srow = 32 * wave + (lane >> 2);
    const int scol = (lane & 3) * 8;
    f32x4 acc[4][4];
    #pragma unroll
    for (int m = 0; m < 4; ++m)
        #pragma unroll
        for (int n = 0; n < 4; ++n) acc[m][n] = (f32x4){0.f, 0.f, 0.f, 0.f};
    for (int pass = 0; pass < 2; ++pass) {
        const unsigned short* A  = pass ? A2 : A1;
        const unsigned short* WT = pass ? WT2 : WT1;
        for (int k0 = 0; k0 < 1024; k0 += 32) {
            __syncthreads();
            #pragma unroll
            for (int i = 0; i < 2; ++i) {
                async16(A  + (size_t)(brow + srow + 16 * i) * 1024 + k0 + scol, &As[(32 * wave + 16 * i) * 32]);
                async16(WT + (size_t)(bcol + srow + 16 * i) * 1024 + k0 + scol, &Bs[(32 * wave + 16 * i) * 32]);
            }
            __syncthreads();
            s16x8 af[4], bf[4];
            #pragma unroll
            for (int m = 0; m < 4; ++m) af[m] = *(const s16x8*)&As[(64 * wm + 16 * m + lr) * 32 + g8];
            #pragma unroll
            for (int n = 0; n < 4; ++n) bf[n] = *(const s16x8*)&Bs[(64 * wn + 16 * n + lr) * 32 + g8];
            #pragma unroll
            for (int m = 0; m < 4; ++m)
                #pragma unroll
                for (int n = 0; n < 4; ++n)
                    acc[m][n] = __builtin_amdgcn_mfma_f32_16x16x32_bf16(af[m], bf[n], acc[m][n], 0, 0, 0);
        }
    }
    const int rg = (lane >> 4) * 4;
    #pragma unroll
    for (int m = 0; m < 4; ++m)
        #pragma unroll
        for (int j = 0; j < 4; ++j) {
            int row = brow + 64 * wm + 16 * m + rg + j;
            float g = G[row];
            #pragma unroll
            for (int n = 0; n < 4; ++n) {
                int col = bcol + 64 * wn + 16 * n + lr;
                OUT[(size_t)row * 1024 + col] = acc[m][n][j] + g * b1[col] + (1.f - g) * b2[col];
            }
        }
}

// ---------------- MFMA flash attention (R13/R16 structure: reg-staged K/V, stride 88) ----------------
__global__ __launch_bounds__(512) void flash_mfma(const unsigned short* __restrict__ Qg,
        const unsigned short* __restrict__ Kg, const unsigned short* __restrict__ Vg,
        const float* __restrict__ G, unsigned short* __restrict__ FA) {
    __shared__ unsigned short Ks[2][64 * KST];   // K rows (stride 88: bank-floor)
    __shared__ unsigned short Vt[2][64 * KST];   // Vt[d][perm(k)-granule ^ (d>>3)]
    const int tid = threadIdx.x, wave = tid >> 6, lane = tid & 63;
    const int b = blockIdx.x >> 4, h = blockIdx.x & 15, q0 = blockIdx.y * 256;
    const int lq = lane & 31, hi = lane >> 5;
    const float QSCALE = 0.125f * 1.44269504f;
    const size_t qrow = (size_t)b * Sc + q0 + wave * 32 + lq;
    const size_t qoff = qrow * Dc + h * HDc + 8 * hi;
    s16x8 aq[4];
    #pragma unroll
    for (int dc = 0; dc < 4; ++dc) {
        u16x8 raw = *(const u16x8*)(Qg + qoff + 16 * dc);
        #pragma unroll
        for (int j = 0; j < 8; ++j) aq[dc][j] = (short)f2bf(bf2f(raw[j]) * QSCALE);
    }
    const s16x8 ones = {0x3F80, 0x3F80, 0x3F80, 0x3F80, 0x3F80, 0x3F80, 0x3F80, 0x3F80};
    f32x16 oacc[2], lacc;
    #pragma unroll
    for (int t = 0; t < 2; ++t)
        #pragma unroll
        for (int r = 0; r < 16; ++r) oacc[t][r] = 0.f;
    #pragma unroll
    for (int r = 0; r < 16; ++r) lacc[r] = 0.f;
    const int srow = tid >> 3, sc8 = (tid & 7) * 8, va = tid & 7;
    const int p0 = (srow & 3) | (((srow >> 3) & 1) << 2) | (((srow >> 2) & 1) << 3) | (srow & 0x30);
    const int pg = p0 >> 3, pin = p0 & 7;
    const size_t kvoff = (size_t)h * HDc + sc8;
    {
        size_t gg = ((size_t)b * Sc + srow) * Dc + kvoff;
        u16x8 kreg = *(const u16x8*)(Kg + gg);
        u16x8 vreg = *(const u16x8*)(Vg + gg);
        *(u16x8*)&Ks[0][srow * KST + sc8] = kreg;
        #pragma unroll
        for (int j = 0; j < 8; ++j)
            Vt[0][(sc8 + j) * KST + 8 * (pg ^ va) + pin] = vreg[j];
    }
    __syncthreads();
    int cur = 0;
    for (int t0 = 0; t0 < Sc; t0 += 64) {
        const bool nxt = (t0 + 64) < Sc;
        u16x8 kn, vn;
        if (nxt) {
            size_t gg = ((size_t)b * Sc + t0 + 64 + srow) * Dc + kvoff;
            kn = *(const u16x8*)(Kg + gg);
            vn = *(const u16x8*)(Vg + gg);
        }
        f32x16 s2[2];
        #pragma unroll
        for (int t = 0; t < 2; ++t)
            #pragma unroll
            for (int r = 0; r < 16; ++r) s2[t][r] = 0.f;
        __builtin_amdgcn_s_setprio(1);
        #pragma unroll
        for (int kt2 = 0; kt2 < 2; ++kt2)
            #pragma unroll
            for (int dc = 0; dc < 4; ++dc) {
                s16x8 ak = *(const s16x8*)&Ks[cur][(32 * kt2 + lq) * KST + 16 * dc + 8 * hi];
                s2[kt2] = __builtin_amdgcn_mfma_f32_32x32x16_bf16(ak, aq[dc], s2[kt2], 0, 0, 0);
            }
        __builtin_amdgcn_s_setprio(0);
        #pragma unroll
        for (int t = 0; t < 2; ++t)
            #pragma unroll
            for (int r = 0; r < 16; ++r)
                s2[t][r] = exp2f(s2[t][r]);
        s16x8 pf[4];
        #pragma unroll
        for (int kc = 0; kc < 4; ++kc) {
            const int t = kc >> 1, e = 8 * (kc & 1);
            union { s16x8 v; unsigned u[4]; } w;
            w.u[0] = cvtpk(s2[t][e + 0], s2[t][e + 1]);
            w.u[1] = cvtpk(s2[t][e + 2], s2[t][e + 3]);
            w.u[2] = cvtpk(s2[t][e + 4], s2[t][e + 5]);
            w.u[3] = cvtpk(s2[t][e + 6], s2[t][e + 7]);
            pf[kc] = w.v;
        }
        __builtin_amdgcn_s_setprio(1);
        #pragma unroll
        for (int dtile = 0; dtile < 2; ++dtile) {
            const int row = 32 * dtile + lq;
            const int rsw = (row >> 3) & 7;
            #pragma unroll
            for (int kc = 0; kc < 4; ++kc) {
                const int g = 4 * (kc >> 1) + 2 * (kc & 1) + hi;
                s16x8 av = *(const s16x8*)&Vt[cur][row * KST + 8 * (g ^ rsw)];
                oacc[dtile] = __builtin_amdgcn_mfma_f32_32x32x16_bf16(av, pf[kc], oacc[dtile], 0, 0, 0);
            }
        }
        #pragma unroll
        for (int kc = 0; kc < 4; ++kc)
            lacc = __builtin_amdgcn_mfma_f32_32x32x16_bf16(ones, pf[kc], lacc, 0, 0, 0);
        __builtin_amdgcn_s_setprio(0);
        if (nxt) {
            *(u16x8*)&Ks[cur ^ 1][srow * KST + sc8] = kn;
            #pragma unroll
            for (int j = 0; j < 8; ++j)
                Vt[cur ^ 1][(sc8 + j) * KST + 8 * (pg ^ va) + pin] = vn[j];
        }
        __syncthreads();
        cur ^= 1;
    }
    const float scl = G[qrow] / lacc[0];
    #pragma unroll
    for (int dtile = 0; dtile < 2; ++dtile)
        #pragma unroll
        for (int s = 0; s < 4; ++s) {
            ushort4 o4;
            o4.x = f2bf(oacc[dtile][4 * s + 0] * scl);
            o4.y = f2bf(oacc[dtile][4 * s + 1] * scl);
            o4.z = f2bf(oacc[dtile][4 * s + 2] * scl);
            o4.w = f2bf(oacc[dtile][4 * s + 3] * scl);
            *(ushort4*)(FA + qrow * Dc + h * HDc + 32 * dtile + 8 * s + 4 * hi) = o4;
        }
}

// ---------------- kv stage 1: per-(bh, l-chunk) partial sums ----------------
__global__ __launch_bounds__(256) void kv_part(const unsigned short* __restrict__ KF,
        const unsigned short* __restrict__ VL, float* __restrict__ PART, float* __restrict__ PARTS) {
    __shared__ float Ks[32][68];
    __shared__ float Vs[32][68];
    const int tid = threadIdx.x;
    const int bh = blockIdx.x;
    const int b = bh >> 4, h = bh & 15;
    const int ch = blockIdx.y;
    const int f = tid >> 2;
    const int dg = (tid & 3) << 4;
    float acc[16] = {};
    float ksum = 0.f;
    const int lbeg = ch * (Sc / NCH), lend = lbeg + Sc / NCH;
    for (int l0 = lbeg; l0 < lend; l0 += 32) {
        __syncthreads();
        for (int i = tid; i < 32 * 64 / 4; i += 256) {
            int r = i >> 4, c = (i & 15) << 2;
            size_t gg = ((size_t)(b * Sc + l0 + r) * Hc + h) * 64 + c;
            ushort4 kk = *(const ushort4*)(KF + gg);
            ushort4 vv = *(const ushort4*)(VL + gg);
            Ks[r][c] = bf2f(kk.x); Ks[r][c + 1] = bf2f(kk.y);
            Ks[r][c + 2] = bf2f(kk.z); Ks[r][c + 3] = bf2f(kk.w);
            Vs[r][c] = bf2f(vv.x); Vs[r][c + 1] = bf2f(vv.y);
            Vs[r][c + 2] = bf2f(vv.z); Vs[r][c + 3] = bf2f(vv.w);
        }
        __syncthreads();
        #pragma unroll 4
        for (int ll = 0; ll < 32; ++ll) {
            float kf = Ks[ll][f];
            ksum += kf;
            float4 v0 = *(const float4*)&Vs[ll][dg];
            float4 v1 = *(const float4*)&Vs[ll][dg + 4];
            float4 v2 = *(const float4*)&Vs[ll][dg + 8];
            float4 v3 = *(const float4*)&Vs[ll][dg + 12];
            acc[0] += kf * v0.x; acc[1] += kf * v0.y; acc[2]  += kf * v0.z; acc[3]  += kf * v0.w;
            acc[4] += kf * v1.x; acc[5] += kf * v1.y; acc[6]  += kf * v1.z; acc[7]  += kf * v1.w;
            acc[8] += kf * v2.x; acc[9] += kf * v2.y; acc[10] += kf * v2.z; acc[11] += kf * v2.w;
            acc[12] += kf * v3.x; acc[13] += kf * v3.y; acc[14] += kf * v3.z; acc[15] += kf * v3.w;
        }
    }
    size_t o = (((size_t)ch * 64 + bh) * 64 + f) * 64 + dg;
    *(float4*)(PART + o)      = make_float4(acc[0], acc[1], acc[2], acc[3]);
    *(float4*)(PART + o + 4)  = make_float4(acc[4], acc[5], acc[6], acc[7]);
    *(float4*)(PART + o + 8)  = make_float4(acc[8], acc[9], acc[10], acc[11]);
    *(float4*)(PART + o + 12) = make_float4(acc[12], acc[13], acc[14], acc[15]);
    if ((tid & 3) == 0) PARTS[((size_t)ch * 64 + bh) * 64 + f] = ksum;
}

// ---------------- KVB build: coalesced chunk-reduce into LDS, then LDS-transposed write ----------------
__global__ __launch_bounds__(256) void kvb_build(const float* __restrict__ PART,
        const float* __restrict__ PARTS, unsigned short* __restrict__ KVB) {
    __shared__ float accs[4096];    // [f][n] layout = f*64 + n
    const int bh = blockIdx.x, t = threadIdx.x;
    for (int i = t; i < 4096; i += 256) {
        float v = 0.f;
        #pragma unroll
        for (int ch = 0; ch < NCH; ++ch)
            v += PART[(size_t)ch * 262144 + (size_t)bh * 4096 + i];
        accs[i] = v;
    }
    __syncthreads();
    for (int i = t; i < 80 * 64; i += 256) {
        int n = i >> 6, f = i & 63;
        float v;
        if (n < 64) {
            v = accs[f * 64 + n];
        } else if (n == 64) {
            v = 0.f;
            #pragma unroll
            for (int ch = 0; ch < NCH; ++ch)
                v += PARTS[(size_t)ch * 4096 + bh * 64 + f];
        } else {
            v = 0.f;
        }
        KVB[(size_t)bh * 5120 + i] = f2bf(v);
    }
}

// ---------------- lin via MFMA ----------------
__global__ __launch_bounds__(256) void lin_mfma(const unsigned short* __restrict__ QF,
        const unsigned short* __restrict__ KVB, const float* __restrict__ G,
        unsigned short* __restrict__ LA) {
    __shared__ unsigned short As[128 * 72];
    __shared__ unsigned short Bs[80 * 72];
    const int tid = threadIdx.x, wave = tid >> 6, lane = tid & 63;
    const int bh = blockIdx.y, b = bh >> 4, h = bh & 15;
    const size_t rowg0 = (size_t)b * Sc + blockIdx.x * 128;
    #pragma unroll
    for (int i = 0; i < 4; ++i) {
        int idx = tid + 256 * i;
        int r = idx >> 3, c8 = (idx & 7) * 8;
        *(u16x8*)&As[r * 72 + c8] = *(const u16x8*)(QF + (rowg0 + r) * 1024 + h * 64 + c8);
    }
    #pragma unroll
    for (int i = 0; i < 3; ++i) {
        int idx = tid + 256 * i;
        if (idx < 640) {
            int r = idx >> 3, c8 = (idx & 7) * 8;
            *(u16x8*)&Bs[r * 72 + c8] = *(const u16x8*)(KVB + (size_t)bh * 5120 + r * 64 + c8);
        }
    }
    __syncthreads();
    const int lr = lane & 15, g8 = (lane >> 4) * 8;
    f32x4 acc[2][5];
    #pragma unroll
    for (int m = 0; m < 2; ++m)
        #pragma unroll
        for (int n = 0; n < 5; ++n) acc[m][n] = (f32x4){0.f, 0.f, 0.f, 0.f};
    #pragma unroll
    for (int kc = 0; kc < 2; ++kc) {
        s16x8 af[2];
        #pragma unroll
        for (int m = 0; m < 2; ++m)
            af[m] = *(const s16x8*)&As[(32 * wave + 16 * m + lr) * 72 + kc * 32 + g8];
        #pragma unroll
        for (int n = 0; n < 5; ++n) {
            s16x8 bfv = *(const s16x8*)&Bs[(16 * n + lr) * 72 + kc * 32 + g8];
            #pragma unroll
            for (int m = 0; m < 2; ++m)
                acc[m][n] = __builtin_amdgcn_mfma_f32_16x16x32_bf16(af[m], bfv, acc[m][n], 0, 0, 0);
        }
    }
    const int rg = (lane >> 4) * 4;
    #pragma unroll
    for (int m = 0; m < 2; ++m)
        #pragma unroll
        for (int j = 0; j < 4; ++j) {
            size_t rglob = rowg0 + 32 * wave + 16 * m + rg + j;
            float g = G[rglob];
            float nv = __shfl(acc[m][4][j], lane & 48, 64);
            float inv = (1.f - g) / fmaxf(nv, 1e-6f);
            #pragma unroll
            for (int n = 0; n < 4; ++n)
                LA[rglob * 1024 + h * 64 + 16 * n + lr] = f2bf(acc[m][n][j] * inv);
        }
}

extern "C" void kernel_launch(void* const* d_in, const int* in_sizes, int n_in,
                              void* d_out, int out_size, void* d_ws, size_t ws_size,
                              hipStream_t stream) {
    const float* x   = (const float*)d_in[0];
    const float* fq  = (const float*)d_in[1];
    const float* fk  = (const float*)d_in[2];
    const float* fv  = (const float*)d_in[3];
    const float* fow = (const float*)d_in[4];
    const float* fob = (const float*)d_in[5];
    const float* lq  = (const float*)d_in[6];
    const float* lk  = (const float*)d_in[7];
    const float* lv  = (const float*)d_in[8];
    const float* low = (const float*)d_in[9];
    const float* lob = (const float*)d_in[10];
    const float* fmw = (const float*)d_in[11];
    const float* fmb = (const float*)d_in[12];
    const float* gw  = (const float*)d_in[13];
    const float* gb  = (const float*)d_in[14];
    float* out = (float*)d_out;

    char* p = (char*)d_ws;
    unsigned short* xb = (unsigned short*)p;          p += MAT * 2;
    unsigned short* wt_fq = (unsigned short*)p;       p += (size_t)1024 * 1024 * 2;
    unsigned short* wt_fk = (unsigned short*)p;       p += (size_t)1024 * 1024 * 2;
    unsigned short* wt_fv = (unsigned short*)p;       p += (size_t)1024 * 1024 * 2;
    unsigned short* wt_fo = (unsigned short*)p;       p += (size_t)1024 * 1024 * 2;
    unsigned short* wt_lq = (unsigned short*)p;       p += (size_t)1024 * 1024 * 2;
    unsigned short* wt_lk = (unsigned short*)p;       p += (size_t)1024 * 1024 * 2;
    unsigned short* wt_lv = (unsigned short*)p;       p += (size_t)1024 * 1024 * 2;
    unsigned short* wt_lo = (unsigned short*)p;       p += (size_t)1024 * 1024 * 2;
    unsigned short* P0 = (unsigned short*)p;          p += MAT * 2;
    unsigned short* P1 = (unsigned short*)p;          p += MAT * 2;
    unsigned short* P2 = (unsigned short*)p;          p += MAT * 2;
    unsigned short* FA = (unsigned short*)p;          p += MAT * 2;
    unsigned short* LA = (unsigned short*)p;          p += MAT * 2;
    float* G  = (float*)p;                            p += (size_t)Rc * 4;
    float* PART  = (float*)p;                         p += (size_t)NCH * 64 * 64 * 64 * 4;
    float* PARTS = (float*)p;                         p += (size_t)NCH * 64 * 64 * 4;
    unsigned short* KVB = (unsigned short*)p;         p += (size_t)64 * 80 * 64 * 2;
    unsigned short* W2  = (unsigned short*)p;         p += (size_t)2 * 1024 * 1024 * 2;

    gate_cvt<<<Rc / 4, 256, 0, stream>>>(x, gw, gb, G, xb);
    wtrans<<<dim3(16, 16, 8), 256, 0, stream>>>(fq, fk, fv, fow, lq, lk, lv, low,
            wt_fq, wt_fk, wt_fv, wt_fo, wt_lq, wt_lk, wt_lv, wt_lo);
    w2build<<<dim3(16, 8, 2), 256, 0, stream>>>(wt_lq, wt_lk, fmw, W2, W2 + (size_t)1024 * 1024);

    // linear path: qf/kf computed directly with fused relu+bias (featmap folded into W2)
    gemm3<<<dim3(64, 24), 256, 0, stream>>>(xb, W2, wt_lv, P0, P1, P2, fmb);
    kv_part<<<dim3(Bc * Hc, NCH), 256, 0, stream>>>(P1, P2, PART, PARTS);
    kvb_build<<<64, 256, 0, stream>>>(PART, PARTS, KVB);
    lin_mfma<<<dim3(Sc / 128, 64), 256, 0, stream>>>(P0, KVB, G, LA);

    // flash path (reuses P0..P2)
    gemm3<<<dim3(64, 24), 256, 0, stream>>>(xb, wt_fq, wt_fv, P0, P1, P2, nullptr);
    flash_mfma<<<dim3(64, 8), 512, 0, stream>>>(P0, P1, P2, G, FA);

    // fused gated output projection
    final_gemm<<<dim3(64, 8), 256, 0, stream>>>(FA, wt_fo, LA, wt_lo, fob, lob, G, out);
}